// Round 4
// baseline (698.355 us; speedup 1.0000x reference)
//
#include <hip/hip_runtime.h>
#include <hip/hip_bf16.h>
#include <math.h>

typedef __bf16 bf16;
typedef __bf16 bf16x8 __attribute__((ext_vector_type(8)));
typedef float f32x4 __attribute__((ext_vector_type(4)));

#define SEQ 1024
#define DMODEL 1024

// async global->LDS DMA, 16B per lane, dest = wave-uniform base + lane*16
__device__ __forceinline__ void gld_lds16(const bf16* g, bf16* l) {
    __builtin_amdgcn_global_load_lds(
        (const __attribute__((address_space(1))) unsigned int*)g,
        (__attribute__((address_space(3))) unsigned int*)l, 16, 0, 0);
}

// ---------------------------------------------------------------------------
// Fused transpose + fp32->bf16 convert: out[n*K + k] = (bf16)in[k*N + n]
// ---------------------------------------------------------------------------
__global__ void transpose_f2b(const float* __restrict__ in, bf16* __restrict__ out,
                              int K, int N) {
    __shared__ float tile[32][33];
    int n0 = blockIdx.x * 32, k0 = blockIdx.y * 32;
    int tx = threadIdx.x, ty = threadIdx.y;
#pragma unroll
    for (int i = 0; i < 4; ++i) {
        int kk = ty + i * 8;
        tile[kk][tx] = in[(size_t)(k0 + kk) * N + n0 + tx];
    }
    __syncthreads();
#pragma unroll
    for (int i = 0; i < 4; ++i) {
        int nn = ty + i * 8;
        out[(size_t)(n0 + nn) * K + k0 + tx] = (bf16)tile[tx][nn];
    }
}

// ---------------------------------------------------------------------------
// LayerNorm: fp32 in -> bf16 out. One row (D=1024) per 256-thread block.
// ---------------------------------------------------------------------------
__global__ void ln_f2b(const float* __restrict__ x, const float* __restrict__ g,
                       const float* __restrict__ bta, bf16* __restrict__ y) {
    int row = blockIdx.x, t = threadIdx.x;
    const float* xr = x + (size_t)row * DMODEL;
    float v[4];
#pragma unroll
    for (int i = 0; i < 4; ++i) v[i] = xr[t * 4 + i];
    float s = v[0] + v[1] + v[2] + v[3];
    float s2 = v[0] * v[0] + v[1] * v[1] + v[2] * v[2] + v[3] * v[3];
#pragma unroll
    for (int off = 32; off > 0; off >>= 1) {
        s += __shfl_down(s, off, 64);
        s2 += __shfl_down(s2, off, 64);
    }
    __shared__ float ws1[4], ws2[4];
    __shared__ float mu_s, rstd_s;
    int lane = t & 63, wv = t >> 6;
    if (lane == 0) { ws1[wv] = s; ws2[wv] = s2; }
    __syncthreads();
    if (t == 0) {
        float S1 = ws1[0] + ws1[1] + ws1[2] + ws1[3];
        float S2 = ws2[0] + ws2[1] + ws2[2] + ws2[3];
        float mu = S1 * (1.0f / DMODEL);
        float var = S2 * (1.0f / DMODEL) - mu * mu;
        mu_s = mu;
        rstd_s = rsqrtf(var + 1e-5f);
    }
    __syncthreads();
    float mu = mu_s, rstd = rstd_s;
    bf16* yr = y + (size_t)row * DMODEL;
#pragma unroll
    for (int i = 0; i < 4; ++i) {
        int d = t * 4 + i;
        float o = (v[i] - mu) * rstd * g[d] + bta[d];
        yr[d] = (bf16)o;
    }
}

// ---------------------------------------------------------------------------
// GEMM (128x128, m97 structure): C[M,N] = A[M,K](bf16) @ Bt[N,K](bf16)^T + bias
// mode: 0 = bf16 out, 1 = bf16 out + exact GELU, 2 = fp32 out
// Kept for the N=1024 GEMMs (out-proj, MLP2) where 256^2 tiles would leave
// most CUs idle. Rows here are 64 B (4 granules): the 2-bit chunk swizzle
// already lands at 8 lanes/granule = 4-way effective — leave as-is.
// ---------------------------------------------------------------------------
#define BM 128
#define BN 128
#define BK 32

__global__ __launch_bounds__(256, 2) void gemm_bt(
    const bf16* __restrict__ A, const bf16* __restrict__ Bt,
    const float* __restrict__ bias, void* __restrict__ Cv,
    int M, int N, int K, int mode) {
    __shared__ bf16 sA[BM * BK];   // row-major, 64B rows, chunk-swizzled
    __shared__ bf16 sB[BN * BK];
    int t = threadIdx.x;
    int lane = t & 63, wave = t >> 6;
    int wr = wave >> 1, wc = wave & 1;
    int m0 = blockIdx.y * BM, n0 = blockIdx.x * BN;
    const bf16* Ap = A + (size_t)m0 * K;
    const bf16* Bp = Bt + (size_t)n0 * K;

    int srow = wave * 16 + (lane >> 2);
    int schunk = lane & 3;
    int gcoff = (schunk ^ (srow & 3)) * 8;
    const bf16* gA0 = Ap + (size_t)srow * K + gcoff;
    const bf16* gA1 = Ap + (size_t)(srow + 64) * K + gcoff;
    const bf16* gB0 = Bp + (size_t)srow * K + gcoff;
    const bf16* gB1 = Bp + (size_t)(srow + 64) * K + gcoff;
    bf16* lA0 = sA + wave * 512;
    bf16* lA1 = sA + 2048 + wave * 512;
    bf16* lB0 = sB + wave * 512;
    bf16* lB1 = sB + 2048 + wave * 512;

    f32x4 acc[4][4];
#pragma unroll
    for (int i = 0; i < 4; ++i)
#pragma unroll
        for (int j = 0; j < 4; ++j) acc[i][j] = (f32x4){0.f, 0.f, 0.f, 0.f};

    int mq = lane & 15, quad = lane >> 4;
    int csw = (quad ^ (mq & 3)) * 8;

    for (int k0 = 0; k0 < K; k0 += BK) {
        __syncthreads();
        gld_lds16(gA0 + k0, lA0);
        gld_lds16(gA1 + k0, lA1);
        gld_lds16(gB0 + k0, lB0);
        gld_lds16(gB1 + k0, lB1);
        __syncthreads();
        bf16x8 af[4], bfr[4];
#pragma unroll
        for (int i = 0; i < 4; ++i)
            af[i] = *(const bf16x8*)&sA[(wr * 64 + i * 16 + mq) * BK + csw];
#pragma unroll
        for (int j = 0; j < 4; ++j)
            bfr[j] = *(const bf16x8*)&sB[(wc * 64 + j * 16 + mq) * BK + csw];
#pragma unroll
        for (int i = 0; i < 4; ++i)
#pragma unroll
            for (int j = 0; j < 4; ++j)
                acc[i][j] = __builtin_amdgcn_mfma_f32_16x16x32_bf16(af[i], bfr[j], acc[i][j], 0, 0, 0);
    }

    int cq = lane & 15, rq = (lane >> 4) * 4;
#pragma unroll
    for (int i = 0; i < 4; ++i) {
        int row = m0 + wr * 64 + i * 16 + rq;
#pragma unroll
        for (int j = 0; j < 4; ++j) {
            int col = n0 + wc * 64 + j * 16 + cq;
            float bv = bias ? bias[col] : 0.0f;
#pragma unroll
            for (int r = 0; r < 4; ++r) {
                float v = acc[i][j][r] + bv;
                if (mode == 1) v = 0.5f * v * (1.0f + erff(v * 0.70710678118654752f));
                size_t idx = (size_t)(row + r) * N + col;
                if (mode == 2) ((float*)Cv)[idx] = v;
                else           ((bf16*)Cv)[idx] = (bf16)v;
            }
        }
    }
}

// ---------------------------------------------------------------------------
// gemm256_bt: 256x256 tile, BK=64, 8 waves (2M x 4N), 4-phase-per-K-tile
// pipelined schedule (T1 XCD swizzle + T2 3-bit granule swizzle + T3/T4
// counted vmcnt + T5 setprio). Plain-HIP port of the m201 template.
//  - LDS 128 KiB DYNAMIC: 2 dbuf x (A 32KB + B 32KB). Rows are 64 elems =
//    128 B = exactly 32 banks, so bank position depends ONLY on the 16B
//    granule index -> need a 3-BIT swizzle: physical granule
//    p = (kh*4 + qp) ^ (row & 7). Per ds_read_b128 each granule position
//    then gets 8 lanes (4-way effective, 1.58x) instead of 16 (the 2-bit
//    swizzle left 16 lanes on 4 banks - the m201 structural conflict).
//    Swizzle applied on the *global source* address (gld_lds dest must be
//    linear, m104) and identically on the ds_read side (rule #21).
//  - per K-tile: 4 phases, each {ds_read frag subtile; 2x gld_lds prefetch
//    of tile t+1; s_barrier; 16x MFMA under setprio; s_barrier}.
//  - swap: issue tile t+2's call0 into the just-freed buffer, then
//    s_waitcnt vmcnt(2) (never 0 mid-loop): retires the oldest 8 = exactly
//    all of tile t+1; t+2's 2 loads ride across the barrier.
// Requires M%256==0, N%256==0, K%64==0, K>=128.
// ---------------------------------------------------------------------------
#define GBAR() do { asm volatile("" ::: "memory"); __builtin_amdgcn_sched_barrier(0); \
    __builtin_amdgcn_s_barrier(); __builtin_amdgcn_sched_barrier(0); asm volatile("" ::: "memory"); } while (0)
#define GWAITV2() do { asm volatile("s_waitcnt vmcnt(2)" ::: "memory"); __builtin_amdgcn_sched_barrier(0); } while (0)
#define GWAITV0() do { asm volatile("s_waitcnt vmcnt(0)" ::: "memory"); __builtin_amdgcn_sched_barrier(0); } while (0)

__global__ __launch_bounds__(512, 2) void gemm256_bt(
    const bf16* __restrict__ A, const bf16* __restrict__ Bt,
    const float* __restrict__ bias, void* __restrict__ Cv,
    int M, int N, int K, int mode) {
    extern __shared__ bf16 smem[];   // 2 dbuf x 2 (A,B) x 256*64 bf16 = 128 KiB
    int t = threadIdx.x;
    int lane = t & 63, wave = t >> 6;
    int wr = wave >> 2, wc = wave & 3;     // wave tile: 128 rows x 64 cols

    // T1: bijective XCD-aware block swizzle (m204 variant)
    int nbx = gridDim.x;
    int nwg = nbx * (int)gridDim.y;
    int bid = (int)blockIdx.y * nbx + (int)blockIdx.x;
    int qd = nwg >> 3, rm = nwg & 7;
    int xcd = bid & 7, loc = bid >> 3;
    int wg = (xcd < rm ? xcd * (qd + 1) : rm * (qd + 1) + (xcd - rm) * qd) + loc;
    int m0 = (wg / nbx) * 256, n0 = (wg % nbx) * 256;

    const bf16* Ap = A + (size_t)m0 * K;
    const bf16* Bp = Bt + (size_t)n0 * K;

    // staging geometry: call cl covers rows [cl*64, cl*64+64); wave w owns
    // rows [cl*64 + 8w, +8). lane: row += lane>>3; dest 16B granule
    // g8 = lane&7 at that row physically holds logical granule g8^(row&7),
    // so the source fetches elems (g8^(sr&7))*8. (row&7 == sr&7: wave*8 and
    // cl*64 are both multiples of 8.)
    int sr = lane >> 3;
    int g8 = lane & 7;
    int soff = (g8 ^ (sr & 7)) * 8;        // pre-swizzled src elem offset
    const bf16* gA = Ap + (size_t)(wave * 8 + sr) * K + soff;
    const bf16* gB = Bp + (size_t)(wave * 8 + sr) * K + soff;

    // fragment read geometry: logical granule kh*4+quad at row rw lives at
    // physical granule (kh*4+quad)^(rw&7); rw&7 == mq&7 for every fragment
    // row (A: wr*128+ih*64+i*16+mq; B: wc*64+jh*32+j*16+mq — all offsets
    // are multiples of 8 except mq). kh=0 offset fro, kh=1 offset fro^32
    // (since ((4+quad)^x)*8 == ((quad^x)*8)^32 for quad<4).
    int mq = lane & 15, quad = lane >> 4;
    int fro = (quad ^ (mq & 7)) * 8;

    f32x4 acc[8][4];
#pragma unroll
    for (int i = 0; i < 8; ++i)
#pragma unroll
        for (int j = 0; j < 4; ++j) acc[i][j] = (f32x4){0.f, 0.f, 0.f, 0.f};

    bf16x8 af[4][2], bq[2][2];
    const bf16 *sA, *sB;
    int nt = K >> 6;

#define SMP(b, ab) (smem + ((size_t)((b) * 2 + (ab))) * 16384)
#define STG(b, cl, tt) do { \
    gld_lds16(gA + (size_t)(cl) * 64 * K + (size_t)(tt) * 64, SMP(b, 0) + ((cl) * 64 + wave * 8) * 64); \
    gld_lds16(gB + (size_t)(cl) * 64 * K + (size_t)(tt) * 64, SMP(b, 1) + ((cl) * 64 + wave * 8) * 64); \
} while (0)
#define LDA(ih) do { _Pragma("unroll") for (int i = 0; i < 4; ++i) { \
    int rw = wr * 128 + (ih) * 64 + i * 16 + mq; \
    af[i][0] = *(const bf16x8*)&sA[rw * 64 + fro]; \
    af[i][1] = *(const bf16x8*)&sA[rw * 64 + (fro ^ 32)]; } } while (0)
#define LDB(jh) do { _Pragma("unroll") for (int j = 0; j < 2; ++j) { \
    int rw = wc * 64 + (jh) * 32 + j * 16 + mq; \
    bq[j][0] = *(const bf16x8*)&sB[rw * 64 + fro]; \
    bq[j][1] = *(const bf16x8*)&sB[rw * 64 + (fro ^ 32)]; } } while (0)
#define MM(ih, jh) do { __builtin_amdgcn_s_setprio(1); \
    _Pragma("unroll") for (int j = 0; j < 2; ++j) \
    _Pragma("unroll") for (int i = 0; i < 4; ++i) { \
        acc[(ih) * 4 + i][(jh) * 2 + j] = __builtin_amdgcn_mfma_f32_16x16x32_bf16( \
            af[i][0], bq[j][0], acc[(ih) * 4 + i][(jh) * 2 + j], 0, 0, 0); \
        acc[(ih) * 4 + i][(jh) * 2 + j] = __builtin_amdgcn_mfma_f32_16x16x32_bf16( \
            af[i][1], bq[j][1], acc[(ih) * 4 + i][(jh) * 2 + j], 0, 0, 0); } \
    __builtin_amdgcn_s_setprio(0); } while (0)

    // prologue: full tile 0 (8 loads) + tile 1 call 0 (2 loads); vmcnt(2)
    // retires exactly tile 0's 8.
#pragma unroll
    for (int cl = 0; cl < 4; ++cl) STG(0, cl, 0);
    if (nt > 1) { STG(1, 0, 1); GWAITV2(); } else { GWAITV0(); }
    GBAR();

    for (int tt = 0; tt < nt; ++tt) {
        int b = tt & 1;
        sA = SMP(b, 0);
        sB = SMP(b, 1);
        int pf = (tt + 1 < nt);
        // phase 0: quadrant (m-half 0, n-half 0)
        LDA(0); LDB(0);
        if (pf) STG(b ^ 1, 1, tt + 1);
        GBAR();
        MM(0, 0);
        GBAR();
        // phase 1: (0,1) — reuse A regs
        LDB(1);
        if (pf) STG(b ^ 1, 2, tt + 1);
        GBAR();
        MM(0, 1);
        GBAR();
        // phase 2: (1,1) — reuse B regs
        LDA(1);
        if (pf) STG(b ^ 1, 3, tt + 1);
        GBAR();
        MM(1, 1);
        GBAR();
        // phase 3: (1,0) — reload B half 0
        LDB(0);
        GBAR();
        MM(1, 0);
        GBAR();
        // swap: keep tile tt+2's call0 (2 loads) in flight across the wait.
        // WAR on buf b rows [0,64) is safe: phase-3 ds_reads completed before
        // each wave's MM issue, ordered before STG by the barrier above.
        if (pf) {
            if (tt + 2 < nt) { STG(b, 0, tt + 2); GWAITV2(); }
            else             { GWAITV0(); }
            GBAR();
        }
    }

#undef SMP
#undef STG
#undef LDA
#undef LDB
#undef MM

    int cq = lane & 15, rq = (lane >> 4) * 4;
#pragma unroll
    for (int i = 0; i < 8; ++i) {
        int row = m0 + wr * 128 + i * 16 + rq;
#pragma unroll
        for (int j = 0; j < 4; ++j) {
            int col = n0 + wc * 64 + j * 16 + cq;
            float bv = bias ? bias[col] : 0.0f;
#pragma unroll
            for (int r = 0; r < 4; ++r) {
                float v = acc[i][j][r] + bv;
                if (mode == 1) v = 0.5f * v * (1.0f + erff(v * 0.70710678118654752f));
                size_t idx = (size_t)(row + r) * N + col;
                if (mode == 2) ((float*)Cv)[idx] = v;
                else           ((bf16*)Cv)[idx] = (bf16)v;
            }
        }
    }
}

// ---------------------------------------------------------------------------
// MFMA flash attention. Block = one (b,h) x 64 Q rows; 4 waves x 16 rows.
// ---------------------------------------------------------------------------
#define LDK 72

__global__ __launch_bounds__(256, 2) void attn_mfma(const bf16* __restrict__ qkv,
                                                    bf16* __restrict__ ao) {
    __shared__ bf16 Klds[64][LDK];
    __shared__ bf16 Vtlds[64][LDK];     // [d][key]
    __shared__ bf16 Plds[4][16][LDK];
    int t = threadIdx.x, lane = t & 63, wave = t >> 6;
    int bh = blockIdx.y, bb = bh >> 4, h = bh & 15;
    int q0 = blockIdx.x * 64;
    const bf16* base = qkv + (size_t)bb * SEQ * 3072;
    int m = lane & 15, quad = lane >> 4;
    int kq = quad * 8;

    bf16x8 qf[2];
    {
        int qrow = q0 + wave * 16 + m;
        const bf16* p = base + (size_t)qrow * 3072 + h * 64;
#pragma unroll
        for (int c = 0; c < 2; ++c) {
            bf16x8 tmp = *(const bf16x8*)(p + c * 32 + kq);
#pragma unroll
            for (int j = 0; j < 8; ++j) qf[c][j] = (bf16)((float)tmp[j] * 0.125f);
        }
    }

    float m_run[4], l_run[4];
    f32x4 o_acc[4];
#pragma unroll
    for (int r = 0; r < 4; ++r) { m_run[r] = -3e38f; l_run[r] = 0.f; }
#pragma unroll
    for (int g = 0; g < 4; ++g) o_acc[g] = (f32x4){0.f, 0.f, 0.f, 0.f};

    int skey = t >> 3, sd0 = (t & 7) * 8;
    int rot = t & 7;

    for (int kt = 0; kt < 16; ++kt) {
        __syncthreads();
        {
            const bf16* pk = base + (size_t)(kt * 64 + skey) * 3072 + 1024 + h * 64 + sd0;
            *(bf16x8*)&Klds[skey][sd0]      = *(const bf16x8*)pk;
            *(bf16x8*)&Klds[skey + 32][sd0] = *(const bf16x8*)(pk + 32 * 3072);
            const bf16* pv = base + (size_t)(kt * 64 + skey) * 3072 + 2048 + h * 64 + sd0;
            bf16x8 v0 = *(const bf16x8*)pv;
            bf16x8 v1 = *(const bf16x8*)(pv + 32 * 3072);
#pragma unroll
            for (int ii = 0; ii < 8; ++ii) {
                int j = (ii + rot) & 7;
                Vtlds[sd0 + j][skey]      = v0[j];
                Vtlds[sd0 + j][skey + 32] = v1[j];
            }
        }
        __syncthreads();

        f32x4 s[4];
#pragma unroll
        for (int g = 0; g < 4; ++g) {
            bf16x8 b0 = *(const bf16x8*)&Klds[g * 16 + m][kq];
            bf16x8 b1 = *(const bf16x8*)&Klds[g * 16 + m][32 + kq];
            s[g] = (f32x4){0.f, 0.f, 0.f, 0.f};
            s[g] = __builtin_amdgcn_mfma_f32_16x16x32_bf16(qf[0], b0, s[g], 0, 0, 0);
            s[g] = __builtin_amdgcn_mfma_f32_16x16x32_bf16(qf[1], b1, s[g], 0, 0, 0);
        }

#pragma unroll
        for (int r = 0; r < 4; ++r) {
            float mx = fmaxf(fmaxf(s[0][r], s[1][r]), fmaxf(s[2][r], s[3][r]));
#pragma unroll
            for (int msk = 1; msk < 16; msk <<= 1) mx = fmaxf(mx, __shfl_xor(mx, msk, 64));
            float m_new = fmaxf(m_run[r], mx);
            float alpha = __expf(m_run[r] - m_new);
            m_run[r] = m_new;
            float rowsum = 0.f;
#pragma unroll
            for (int g = 0; g < 4; ++g) {
                float p = __expf(s[g][r] - m_new);
                s[g][r] = p;
                rowsum += p;
            }
#pragma unroll
            for (int msk = 1; msk < 16; msk <<= 1) rowsum += __shfl_xor(rowsum, msk, 64);
            l_run[r] = l_run[r] * alpha + rowsum;
#pragma unroll
            for (int g = 0; g < 4; ++g) o_acc[g][r] *= alpha;
        }

#pragma unroll
        for (int g = 0; g < 4; ++g)
#pragma unroll
            for (int r = 0; r < 4; ++r)
                Plds[wave][quad * 4 + r][g * 16 + m] = (bf16)s[g][r];

#pragma unroll
        for (int kc = 0; kc < 2; ++kc) {
            bf16x8 pf = *(const bf16x8*)&Plds[wave][m][kc * 32 + kq];
#pragma unroll
            for (int dg = 0; dg < 4; ++dg) {
                bf16x8 vf = *(const bf16x8*)&Vtlds[dg * 16 + m][kc * 32 + kq];
                o_acc[dg] = __builtin_amdgcn_mfma_f32_16x16x32_bf16(pf, vf, o_acc[dg], 0, 0, 0);
            }
        }
    }

#pragma unroll
    for (int r = 0; r < 4; ++r) {
        int row = q0 + wave * 16 + quad * 4 + r;
        float rl = 1.0f / l_run[r];
        bf16* op = ao + ((size_t)bb * SEQ + row) * DMODEL + h * 64;
#pragma unroll
        for (int g = 0; g < 4; ++g) op[g * 16 + m] = (bf16)(o_acc[g][r] * rl);
    }
}

// ---------------------------------------------------------------------------
// kernel_launch — fp32 I/O, bf16 internal. ws peak 56 MiB; d_out (32 MB) used
// as scratch (xn/ao in [0,16M), x2n in [16M,32M), final fp32 out last).
// Large-N GEMMs (QKV N=3072, MLP1 N=4096) -> gemm256_bt (4-phase, 384/256
// blocks, 128 KiB dynamic LDS); N=1024 GEMMs stay on 128^2 gemm_bt.
// ---------------------------------------------------------------------------
extern "C" void kernel_launch(void* const* d_in, const int* in_sizes, int n_in,
                              void* d_out, int out_size, void* d_ws, size_t ws_size,
                              hipStream_t stream) {
    const float* x     = (const float*)d_in[0];
    const float* ln1_g = (const float*)d_in[1];
    const float* ln1_b = (const float*)d_in[2];
    const float* w_qkv = (const float*)d_in[3];
    const float* w_out = (const float*)d_in[4];
    const float* b_out = (const float*)d_in[5];
    const float* ln2_g = (const float*)d_in[6];
    const float* ln2_b = (const float*)d_in[7];
    const float* w1    = (const float*)d_in[8];
    const float* b1    = (const float*)d_in[9];
    const float* w2    = (const float*)d_in[10];
    const float* b2    = (const float*)d_in[11];
    float* out = (float*)d_out;
    char* ws = (char*)d_ws;
    char* outc = (char*)d_out;

    // one-time: allow 128 KiB dynamic LDS on gemm256_bt (host attr call, not
    // a stream op — graph-capture safe)
    static bool lds_init = false;
    if (!lds_init) {
        hipFuncSetAttribute((const void*)gemm256_bt,
                            hipFuncAttributeMaxDynamicSharedMemorySize, 131072);
        lds_init = true;
    }

    bf16* wqkvT = (bf16*)(ws + (0ull << 20));
    bf16* woutT = (bf16*)(ws + (6ull << 20));
    bf16* qkv   = (bf16*)(ws + (8ull << 20));
    bf16* w1T   = (bf16*)(ws + (8ull << 20));    // over dead qkv (after attn)
    bf16* w2T   = (bf16*)(ws + (16ull << 20));   // over dead qkv (after attn)
    float* x2   = (float*)(ws + (24ull << 20));  // over dead qkv (after attn)
    bf16* hbuf  = (bf16*)(ws + (24ull << 20));   // over dead x2 (after ln2)
    bf16* xn    = (bf16*)(outc + 0);             // d_out as scratch
    bf16* ao    = (bf16*)(outc + 0);             // xn dead
    bf16* x2n   = (bf16*)(outc + (16ull << 20)); // upper half of d_out

    dim3 tb(32, 8);
    transpose_f2b<<<dim3(3072 / 32, 1024 / 32), tb, 0, stream>>>(w_qkv, wqkvT, 1024, 3072);
    transpose_f2b<<<dim3(1024 / 32, 1024 / 32), tb, 0, stream>>>(w_out, woutT, 1024, 1024);

    ln_f2b<<<8192, 256, 0, stream>>>(x, ln1_g, ln1_b, xn);
    gemm256_bt<<<dim3(3072 / 256, 8192 / 256), 512, 131072, stream>>>(xn, wqkvT, nullptr, qkv,
                                                                      8192, 3072, 1024, 0);
    attn_mfma<<<dim3(SEQ / 64, 128), 256, 0, stream>>>(qkv, ao);

    transpose_f2b<<<dim3(4096 / 32, 1024 / 32), tb, 0, stream>>>(w1, w1T, 1024, 4096);
    transpose_f2b<<<dim3(1024 / 32, 4096 / 32), tb, 0, stream>>>(w2, w2T, 4096, 1024);

    gemm_bt<<<dim3(1024 / 128, 8192 / 128), 256, 0, stream>>>(ao, woutT, b_out, x2,
                                                              8192, 1024, 1024, 2);
    ln_f2b<<<8192, 256, 0, stream>>>(x2, ln2_g, ln2_b, x2n);

    for (int c = 0; c < 2; ++c) {
        const bf16* a1 = x2n + (size_t)c * 4096 * 1024;
        float* oc = out + (size_t)c * 4096 * 1024;
        gemm256_bt<<<dim3(4096 / 256, 4096 / 256), 512, 131072, stream>>>(a1, w1T, b1, hbuf,
                                                                          4096, 4096, 1024, 1);
        gemm_bt<<<dim3(1024 / 128, 4096 / 128), 256, 0, stream>>>(hbuf, w2T, b2, oc,
                                                                  4096, 1024, 4096, 2);
    }
}

// Round 5
// 697.596 us; speedup vs baseline: 1.0011x; 1.0011x over previous
//
#include <hip/hip_runtime.h>
#include <hip/hip_bf16.h>
#include <math.h>

typedef __bf16 bf16;
typedef __bf16 bf16x8 __attribute__((ext_vector_type(8)));
typedef float f32x4 __attribute__((ext_vector_type(4)));

#define SEQ 1024
#define DMODEL 1024

// async global->LDS DMA, 16B per lane, dest = wave-uniform base + lane*16
__device__ __forceinline__ void gld_lds16(const bf16* g, bf16* l) {
    __builtin_amdgcn_global_load_lds(
        (const __attribute__((address_space(1))) unsigned int*)g,
        (__attribute__((address_space(3))) unsigned int*)l, 16, 0, 0);
}

// ---------------------------------------------------------------------------
// Fused transpose + fp32->bf16 convert: out[n*K + k] = (bf16)in[k*N + n]
// ---------------------------------------------------------------------------
__global__ void transpose_f2b(const float* __restrict__ in, bf16* __restrict__ out,
                              int K, int N) {
    __shared__ float tile[32][33];
    int n0 = blockIdx.x * 32, k0 = blockIdx.y * 32;
    int tx = threadIdx.x, ty = threadIdx.y;
#pragma unroll
    for (int i = 0; i < 4; ++i) {
        int kk = ty + i * 8;
        tile[kk][tx] = in[(size_t)(k0 + kk) * N + n0 + tx];
    }
    __syncthreads();
#pragma unroll
    for (int i = 0; i < 4; ++i) {
        int nn = ty + i * 8;
        out[(size_t)(n0 + nn) * K + k0 + tx] = (bf16)tile[tx][nn];
    }
}

// ---------------------------------------------------------------------------
// LayerNorm: fp32 in -> bf16 out. One row (D=1024) per 256-thread block.
// ---------------------------------------------------------------------------
__global__ void ln_f2b(const float* __restrict__ x, const float* __restrict__ g,
                       const float* __restrict__ bta, bf16* __restrict__ y) {
    int row = blockIdx.x, t = threadIdx.x;
    const float* xr = x + (size_t)row * DMODEL;
    float v[4];
#pragma unroll
    for (int i = 0; i < 4; ++i) v[i] = xr[t * 4 + i];
    float s = v[0] + v[1] + v[2] + v[3];
    float s2 = v[0] * v[0] + v[1] * v[1] + v[2] * v[2] + v[3] * v[3];
#pragma unroll
    for (int off = 32; off > 0; off >>= 1) {
        s += __shfl_down(s, off, 64);
        s2 += __shfl_down(s2, off, 64);
    }
    __shared__ float ws1[4], ws2[4];
    __shared__ float mu_s, rstd_s;
    int lane = t & 63, wv = t >> 6;
    if (lane == 0) { ws1[wv] = s; ws2[wv] = s2; }
    __syncthreads();
    if (t == 0) {
        float S1 = ws1[0] + ws1[1] + ws1[2] + ws1[3];
        float S2 = ws2[0] + ws2[1] + ws2[2] + ws2[3];
        float mu = S1 * (1.0f / DMODEL);
        float var = S2 * (1.0f / DMODEL) - mu * mu;
        mu_s = mu;
        rstd_s = rsqrtf(var + 1e-5f);
    }
    __syncthreads();
    float mu = mu_s, rstd = rstd_s;
    bf16* yr = y + (size_t)row * DMODEL;
#pragma unroll
    for (int i = 0; i < 4; ++i) {
        int d = t * 4 + i;
        float o = (v[i] - mu) * rstd * g[d] + bta[d];
        yr[d] = (bf16)o;
    }
}

// ---------------------------------------------------------------------------
// GEMM (128x128, m97 structure): C[M,N] = A[M,K](bf16) @ Bt[N,K](bf16)^T + bias
// mode: 0 = bf16 out, 1 = bf16 out + exact GELU, 2 = fp32 out
// ---------------------------------------------------------------------------
#define BM 128
#define BN 128
#define BK 32

__global__ __launch_bounds__(256, 2) void gemm_bt(
    const bf16* __restrict__ A, const bf16* __restrict__ Bt,
    const float* __restrict__ bias, void* __restrict__ Cv,
    int M, int N, int K, int mode) {
    __shared__ bf16 sA[BM * BK];   // row-major, 64B rows, chunk-swizzled
    __shared__ bf16 sB[BN * BK];
    int t = threadIdx.x;
    int lane = t & 63, wave = t >> 6;
    int wr = wave >> 1, wc = wave & 1;
    int m0 = blockIdx.y * BM, n0 = blockIdx.x * BN;
    const bf16* Ap = A + (size_t)m0 * K;
    const bf16* Bp = Bt + (size_t)n0 * K;

    int srow = wave * 16 + (lane >> 2);
    int schunk = lane & 3;
    int gcoff = (schunk ^ (srow & 3)) * 8;
    const bf16* gA0 = Ap + (size_t)srow * K + gcoff;
    const bf16* gA1 = Ap + (size_t)(srow + 64) * K + gcoff;
    const bf16* gB0 = Bp + (size_t)srow * K + gcoff;
    const bf16* gB1 = Bp + (size_t)(srow + 64) * K + gcoff;
    bf16* lA0 = sA + wave * 512;
    bf16* lA1 = sA + 2048 + wave * 512;
    bf16* lB0 = sB + wave * 512;
    bf16* lB1 = sB + 2048 + wave * 512;

    f32x4 acc[4][4];
#pragma unroll
    for (int i = 0; i < 4; ++i)
#pragma unroll
        for (int j = 0; j < 4; ++j) acc[i][j] = (f32x4){0.f, 0.f, 0.f, 0.f};

    int mq = lane & 15, quad = lane >> 4;
    int csw = (quad ^ (mq & 3)) * 8;

    for (int k0 = 0; k0 < K; k0 += BK) {
        __syncthreads();
        gld_lds16(gA0 + k0, lA0);
        gld_lds16(gA1 + k0, lA1);
        gld_lds16(gB0 + k0, lB0);
        gld_lds16(gB1 + k0, lB1);
        __syncthreads();
        bf16x8 af[4], bfr[4];
#pragma unroll
        for (int i = 0; i < 4; ++i)
            af[i] = *(const bf16x8*)&sA[(wr * 64 + i * 16 + mq) * BK + csw];
#pragma unroll
        for (int j = 0; j < 4; ++j)
            bfr[j] = *(const bf16x8*)&sB[(wc * 64 + j * 16 + mq) * BK + csw];
#pragma unroll
        for (int i = 0; i < 4; ++i)
#pragma unroll
            for (int j = 0; j < 4; ++j)
                acc[i][j] = __builtin_amdgcn_mfma_f32_16x16x32_bf16(af[i], bfr[j], acc[i][j], 0, 0, 0);
    }

    int cq = lane & 15, rq = (lane >> 4) * 4;
#pragma unroll
    for (int i = 0; i < 4; ++i) {
        int row = m0 + wr * 64 + i * 16 + rq;
#pragma unroll
        for (int j = 0; j < 4; ++j) {
            int col = n0 + wc * 64 + j * 16 + cq;
            float bv = bias ? bias[col] : 0.0f;
#pragma unroll
            for (int r = 0; r < 4; ++r) {
                float v = acc[i][j][r] + bv;
                if (mode == 1) v = 0.5f * v * (1.0f + erff(v * 0.70710678118654752f));
                size_t idx = (size_t)(row + r) * N + col;
                if (mode == 2) ((float*)Cv)[idx] = v;
                else           ((bf16*)Cv)[idx] = (bf16)v;
            }
        }
    }
}

// ---------------------------------------------------------------------------
// gemm256_bt: 256x256 tile, BK=64, 8 waves, 4-phase pipelined schedule
// (verified correct R4). Unchanged this round.
// ---------------------------------------------------------------------------
#define GBAR() do { asm volatile("" ::: "memory"); __builtin_amdgcn_sched_barrier(0); \
    __builtin_amdgcn_s_barrier(); __builtin_amdgcn_sched_barrier(0); asm volatile("" ::: "memory"); } while (0)
#define GWAITV2() do { asm volatile("s_waitcnt vmcnt(2)" ::: "memory"); __builtin_amdgcn_sched_barrier(0); } while (0)
#define GWAITV0() do { asm volatile("s_waitcnt vmcnt(0)" ::: "memory"); __builtin_amdgcn_sched_barrier(0); } while (0)

__global__ __launch_bounds__(512, 2) void gemm256_bt(
    const bf16* __restrict__ A, const bf16* __restrict__ Bt,
    const float* __restrict__ bias, void* __restrict__ Cv,
    int M, int N, int K, int mode) {
    extern __shared__ bf16 smem[];   // 2 dbuf x 2 (A,B) x 256*64 bf16 = 128 KiB
    int t = threadIdx.x;
    int lane = t & 63, wave = t >> 6;
    int wr = wave >> 2, wc = wave & 3;     // wave tile: 128 rows x 64 cols

    // T1: bijective XCD-aware block swizzle (m204 variant)
    int nbx = gridDim.x;
    int nwg = nbx * (int)gridDim.y;
    int bid = (int)blockIdx.y * nbx + (int)blockIdx.x;
    int qd = nwg >> 3, rm = nwg & 7;
    int xcd = bid & 7, loc = bid >> 3;
    int wg = (xcd < rm ? xcd * (qd + 1) : rm * (qd + 1) + (xcd - rm) * qd) + loc;
    int m0 = (wg / nbx) * 256, n0 = (wg % nbx) * 256;

    const bf16* Ap = A + (size_t)m0 * K;
    const bf16* Bp = Bt + (size_t)n0 * K;

    int sr = lane >> 3;
    int g8 = lane & 7;
    int soff = (g8 ^ (sr & 7)) * 8;        // pre-swizzled src elem offset (3-bit)
    const bf16* gA = Ap + (size_t)(wave * 8 + sr) * K + soff;
    const bf16* gB = Bp + (size_t)(wave * 8 + sr) * K + soff;

    int mq = lane & 15, quad = lane >> 4;
    int fro = (quad ^ (mq & 7)) * 8;

    f32x4 acc[8][4];
#pragma unroll
    for (int i = 0; i < 8; ++i)
#pragma unroll
        for (int j = 0; j < 4; ++j) acc[i][j] = (f32x4){0.f, 0.f, 0.f, 0.f};

    bf16x8 af[4][2], bq[2][2];
    const bf16 *sA, *sB;
    int nt = K >> 6;

#define SMP(b, ab) (smem + ((size_t)((b) * 2 + (ab))) * 16384)
#define STG(b, cl, tt) do { \
    gld_lds16(gA + (size_t)(cl) * 64 * K + (size_t)(tt) * 64, SMP(b, 0) + ((cl) * 64 + wave * 8) * 64); \
    gld_lds16(gB + (size_t)(cl) * 64 * K + (size_t)(tt) * 64, SMP(b, 1) + ((cl) * 64 + wave * 8) * 64); \
} while (0)
#define LDA(ih) do { _Pragma("unroll") for (int i = 0; i < 4; ++i) { \
    int rw = wr * 128 + (ih) * 64 + i * 16 + mq; \
    af[i][0] = *(const bf16x8*)&sA[rw * 64 + fro]; \
    af[i][1] = *(const bf16x8*)&sA[rw * 64 + (fro ^ 32)]; } } while (0)
#define LDB(jh) do { _Pragma("unroll") for (int j = 0; j < 2; ++j) { \
    int rw = wc * 64 + (jh) * 32 + j * 16 + mq; \
    bq[j][0] = *(const bf16x8*)&sB[rw * 64 + fro]; \
    bq[j][1] = *(const bf16x8*)&sB[rw * 64 + (fro ^ 32)]; } } while (0)
#define MM(ih, jh) do { __builtin_amdgcn_s_setprio(1); \
    _Pragma("unroll") for (int j = 0; j < 2; ++j) \
    _Pragma("unroll") for (int i = 0; i < 4; ++i) { \
        acc[(ih) * 4 + i][(jh) * 2 + j] = __builtin_amdgcn_mfma_f32_16x16x32_bf16( \
            af[i][0], bq[j][0], acc[(ih) * 4 + i][(jh) * 2 + j], 0, 0, 0); \
        acc[(ih) * 4 + i][(jh) * 2 + j] = __builtin_amdgcn_mfma_f32_16x16x32_bf16( \
            af[i][1], bq[j][1], acc[(ih) * 4 + i][(jh) * 2 + j], 0, 0, 0); } \
    __builtin_amdgcn_s_setprio(0); } while (0)

#pragma unroll
    for (int cl = 0; cl < 4; ++cl) STG(0, cl, 0);
    if (nt > 1) { STG(1, 0, 1); GWAITV2(); } else { GWAITV0(); }
    GBAR();

    for (int tt = 0; tt < nt; ++tt) {
        int b = tt & 1;
        sA = SMP(b, 0);
        sB = SMP(b, 1);
        int pf = (tt + 1 < nt);
        LDA(0); LDB(0);
        if (pf) STG(b ^ 1, 1, tt + 1);
        GBAR();
        MM(0, 0);
        GBAR();
        LDB(1);
        if (pf) STG(b ^ 1, 2, tt + 1);
        GBAR();
        MM(0, 1);
        GBAR();
        LDA(1);
        if (pf) STG(b ^ 1, 3, tt + 1);
        GBAR();
        MM(1, 1);
        GBAR();
        LDB(0);
        GBAR();
        MM(1, 0);
        GBAR();
        if (pf) {
            if (tt + 2 < nt) { STG(b, 0, tt + 2); GWAITV2(); }
            else             { GWAITV0(); }
            GBAR();
        }
    }

#undef SMP
#undef STG
#undef LDA
#undef LDB
#undef MM

    int cq = lane & 15, rq = (lane >> 4) * 4;
#pragma unroll
    for (int i = 0; i < 8; ++i) {
        int row = m0 + wr * 128 + i * 16 + rq;
#pragma unroll
        for (int j = 0; j < 4; ++j) {
            int col = n0 + wc * 64 + j * 16 + cq;
            float bv = bias ? bias[col] : 0.0f;
#pragma unroll
            for (int r = 0; r < 4; ++r) {
                float v = acc[i][j][r] + bv;
                if (mode == 1) v = 0.5f * v * (1.0f + erff(v * 0.70710678118654752f));
                size_t idx = (size_t)(row + r) * N + col;
                if (mode == 2) ((float*)Cv)[idx] = v;
                else           ((bf16*)Cv)[idx] = (bf16)v;
            }
        }
    }
}

// ---------------------------------------------------------------------------
// MFMA flash attention v2. Block = one (b,h) x 64 Q rows; 4 waves x 16 rows.
// R4 counters: 147us, MfmaUtil 9.8%, VALUBusy 54%, FETCH 139MB (L2 dup).
// Changes vs v1 (all attn-local):
//  - KVBLK 64->128: halves softmax passes, barrier pairs, staging setups
//    per key. LDS 27.6->53.2 KB (3 blocks/CU).
//  - T14 async-STAGE: global K/V loads for tile kt+1 issued into REGISTERS at
//    the top of iteration kt (latency hides under QK^T+softmax+PV); ds_write
//    after the end-of-tile barrier. Same 2 barriers/tile.
//  - XCD swizzle (m204, nwg=2048%8==0): 256 consecutive flat ids per XCD so
//    all 16 q-tile blocks of a (b,h) share one L2 copy of K/V.
// ---------------------------------------------------------------------------
#define KVB 128
#define LDK2 72     // Klds row pad (d=64 -> 72)
#define LDP 136     // Vt/P row pad (key=128 -> 136)

__global__ __launch_bounds__(256, 2) void attn_mfma(const bf16* __restrict__ qkv,
                                                    bf16* __restrict__ ao) {
    __shared__ bf16 Klds[KVB][LDK2];    // [key][d]   18,432 B
    __shared__ bf16 Vtlds[64][LDP];     // [d][key]   17,408 B
    __shared__ bf16 Plds[4][16][LDP];   // per-wave P 17,408 B
    int t = threadIdx.x, lane = t & 63, wave = t >> 6;

    // XCD swizzle: flat id -> chunk of 256 per XCD; decode bh = wg>>4 so the
    // 16 q-tiles of each (b,h) stay on one XCD.
    int f = (int)blockIdx.y * (int)gridDim.x + (int)blockIdx.x;  // 0..2047
    int wg = (f & 7) * 256 + (f >> 3);
    int bh = wg >> 4, bb = bh >> 4, h = bh & 15;
    int q0 = (wg & 15) * 64;

    const bf16* base = qkv + (size_t)bb * SEQ * 3072;
    int m = lane & 15, quad = lane >> 4;
    int kq = quad * 8;

    bf16x8 qf[2];
    {
        int qrow = q0 + wave * 16 + m;
        const bf16* p = base + (size_t)qrow * 3072 + h * 64;
#pragma unroll
        for (int c = 0; c < 2; ++c) {
            bf16x8 tmp = *(const bf16x8*)(p + c * 32 + kq);
#pragma unroll
            for (int j = 0; j < 8; ++j) qf[c][j] = (bf16)((float)tmp[j] * 0.125f);
        }
    }

    float m_run[4], l_run[4];
    f32x4 o_acc[4];
#pragma unroll
    for (int r = 0; r < 4; ++r) { m_run[r] = -3e38f; l_run[r] = 0.f; }
#pragma unroll
    for (int g = 0; g < 4; ++g) o_acc[g] = (f32x4){0.f, 0.f, 0.f, 0.f};

    // staging: thread covers K/V rows skey+{0,32,64,96}, d-slice sd0..sd0+8
    int skey = t >> 3, sd0 = (t & 7) * 8;
    int rot = t & 7;
    const bf16* pk0 = base + (size_t)skey * 3072 + 1024 + h * 64 + sd0;
    const bf16* pv0 = base + (size_t)skey * 3072 + 2048 + h * 64 + sd0;

    bf16x8 kreg[4], vreg[4];

#define LOADKV(kt2) do { \
    const bf16* pk = pk0 + (size_t)(kt2) * KVB * 3072; \
    const bf16* pv = pv0 + (size_t)(kt2) * KVB * 3072; \
    _Pragma("unroll") for (int c = 0; c < 4; ++c) { \
        kreg[c] = *(const bf16x8*)(pk + (size_t)c * 32 * 3072); \
        vreg[c] = *(const bf16x8*)(pv + (size_t)c * 32 * 3072); } \
} while (0)
#define WRITEKV() do { \
    _Pragma("unroll") for (int c = 0; c < 4; ++c) { \
        *(bf16x8*)&Klds[skey + c * 32][sd0] = kreg[c]; \
        _Pragma("unroll") for (int ii = 0; ii < 8; ++ii) { \
            int j = (ii + rot) & 7; \
            Vtlds[sd0 + j][skey + c * 32] = vreg[c][j]; } } \
} while (0)

    // prologue: tile 0 -> LDS
    LOADKV(0);
    WRITEKV();
    __syncthreads();

    for (int kt = 0; kt < SEQ / KVB; ++kt) {   // 8 iterations
        if (kt + 1 < SEQ / KVB) LOADKV(kt + 1);   // T14: issue early

        // QK^T: 8 key-groups of 16
        f32x4 s[8];
#pragma unroll
        for (int g = 0; g < 8; ++g) {
            bf16x8 b0 = *(const bf16x8*)&Klds[g * 16 + m][kq];
            bf16x8 b1 = *(const bf16x8*)&Klds[g * 16 + m][32 + kq];
            s[g] = (f32x4){0.f, 0.f, 0.f, 0.f};
            s[g] = __builtin_amdgcn_mfma_f32_16x16x32_bf16(qf[0], b0, s[g], 0, 0, 0);
            s[g] = __builtin_amdgcn_mfma_f32_16x16x32_bf16(qf[1], b1, s[g], 0, 0, 0);
        }

        // online softmax over 128 keys (one pass)
#pragma unroll
        for (int r = 0; r < 4; ++r) {
            float mx = s[0][r];
#pragma unroll
            for (int g = 1; g < 8; ++g) mx = fmaxf(mx, s[g][r]);
#pragma unroll
            for (int msk = 1; msk < 16; msk <<= 1) mx = fmaxf(mx, __shfl_xor(mx, msk, 64));
            float m_new = fmaxf(m_run[r], mx);
            float alpha = __expf(m_run[r] - m_new);
            m_run[r] = m_new;
            float rowsum = 0.f;
#pragma unroll
            for (int g = 0; g < 8; ++g) {
                float p = __expf(s[g][r] - m_new);
                s[g][r] = p;
                rowsum += p;
            }
#pragma unroll
            for (int msk = 1; msk < 16; msk <<= 1) rowsum += __shfl_xor(rowsum, msk, 64);
            l_run[r] = l_run[r] * alpha + rowsum;
#pragma unroll
            for (int g = 0; g < 4; ++g) o_acc[g][r] *= alpha;
        }

        // P -> LDS (per-wave buffer, no barrier needed; lgkmcnt orders reads)
#pragma unroll
        for (int g = 0; g < 8; ++g)
#pragma unroll
            for (int r = 0; r < 4; ++r)
                Plds[wave][quad * 4 + r][g * 16 + m] = (bf16)s[g][r];

        // PV: 4 key-chunks of 32
#pragma unroll
        for (int kc = 0; kc < 4; ++kc) {
            bf16x8 pf = *(const bf16x8*)&Plds[wave][m][kc * 32 + kq];
#pragma unroll
            for (int dg = 0; dg < 4; ++dg) {
                bf16x8 vf = *(const bf16x8*)&Vtlds[dg * 16 + m][kc * 32 + kq];
                o_acc[dg] = __builtin_amdgcn_mfma_f32_16x16x32_bf16(pf, vf, o_acc[dg], 0, 0, 0);
            }
        }

        __syncthreads();                         // all waves done with tile kt
        if (kt + 1 < SEQ / KVB) {
            WRITEKV();                           // regs -> LDS (vmcnt by use)
        }
        __syncthreads();                         // tile kt+1 visible
    }

#undef LOADKV
#undef WRITEKV

#pragma unroll
    for (int r = 0; r < 4; ++r) {
        int row = q0 + wave * 16 + quad * 4 + r;
        float rl = 1.0f / l_run[r];
        bf16* op = ao + ((size_t)bb * SEQ + row) * DMODEL + h * 64;
#pragma unroll
        for (int g = 0; g < 4; ++g) op[g * 16 + m] = (bf16)(o_acc[g][r] * rl);
    }
}

// ---------------------------------------------------------------------------
// kernel_launch — fp32 I/O, bf16 internal. ws peak 56 MiB; d_out (32 MB) used
// as scratch (xn/ao in [0,16M), x2n in [16M,32M), final fp32 out last).
// ---------------------------------------------------------------------------
extern "C" void kernel_launch(void* const* d_in, const int* in_sizes, int n_in,
                              void* d_out, int out_size, void* d_ws, size_t ws_size,
                              hipStream_t stream) {
    const float* x     = (const float*)d_in[0];
    const float* ln1_g = (const float*)d_in[1];
    const float* ln1_b = (const float*)d_in[2];
    const float* w_qkv = (const float*)d_in[3];
    const float* w_out = (const float*)d_in[4];
    const float* b_out = (const float*)d_in[5];
    const float* ln2_g = (const float*)d_in[6];
    const float* ln2_b = (const float*)d_in[7];
    const float* w1    = (const float*)d_in[8];
    const float* b1    = (const float*)d_in[9];
    const float* w2    = (const float*)d_in[10];
    const float* b2    = (const float*)d_in[11];
    float* out = (float*)d_out;
    char* ws = (char*)d_ws;
    char* outc = (char*)d_out;

    static bool lds_init = false;
    if (!lds_init) {
        hipFuncSetAttribute((const void*)gemm256_bt,
                            hipFuncAttributeMaxDynamicSharedMemorySize, 131072);
        lds_init = true;
    }

    bf16* wqkvT = (bf16*)(ws + (0ull << 20));
    bf16* woutT = (bf16*)(ws + (6ull << 20));
    bf16* qkv   = (bf16*)(ws + (8ull << 20));
    bf16* w1T   = (bf16*)(ws + (8ull << 20));    // over dead qkv (after attn)
    bf16* w2T   = (bf16*)(ws + (16ull << 20));   // over dead qkv (after attn)
    float* x2   = (float*)(ws + (24ull << 20));  // over dead qkv (after attn)
    bf16* hbuf  = (bf16*)(ws + (24ull << 20));   // over dead x2 (after ln2)
    bf16* xn    = (bf16*)(outc + 0);             // d_out as scratch
    bf16* ao    = (bf16*)(outc + 0);             // xn dead
    bf16* x2n   = (bf16*)(outc + (16ull << 20)); // upper half of d_out

    dim3 tb(32, 8);
    transpose_f2b<<<dim3(3072 / 32, 1024 / 32), tb, 0, stream>>>(w_qkv, wqkvT, 1024, 3072);
    transpose_f2b<<<dim3(1024 / 32, 1024 / 32), tb, 0, stream>>>(w_out, woutT, 1024, 1024);

    ln_f2b<<<8192, 256, 0, stream>>>(x, ln1_g, ln1_b, xn);
    gemm256_bt<<<dim3(3072 / 256, 8192 / 256), 512, 131072, stream>>>(xn, wqkvT, nullptr, qkv,
                                                                      8192, 3072, 1024, 0);
    attn_mfma<<<dim3(SEQ / 64, 128), 256, 0, stream>>>(qkv, ao);

    transpose_f2b<<<dim3(4096 / 32, 1024 / 32), tb, 0, stream>>>(w1, w1T, 1024, 4096);
    transpose_f2b<<<dim3(1024 / 32, 4096 / 32), tb, 0, stream>>>(w2, w2T, 4096, 1024);

    gemm_bt<<<dim3(1024 / 128, 8192 / 128), 256, 0, stream>>>(ao, woutT, b_out, x2,
                                                              8192, 1024, 1024, 2);
    ln_f2b<<<8192, 256, 0, stream>>>(x2, ln2_g, ln2_b, x2n);

    for (int c = 0; c < 2; ++c) {
        const bf16* a1 = x2n + (size_t)c * 4096 * 1024;
        float* oc = out + (size_t)c * 4096 * 1024;
        gemm256_bt<<<dim3(4096 / 256, 4096 / 256), 512, 131072, stream>>>(a1, w1T, b1, hbuf,
                                                                          4096, 4096, 1024, 1);
        gemm_bt<<<dim3(1024 / 128, 4096 / 128), 256, 0, stream>>>(hbuf, w2T, b2, oc,
                                                                  4096, 1024, 4096, 2);
    }
}

// Round 9
// 623.570 us; speedup vs baseline: 1.1199x; 1.1187x over previous
//
#include <hip/hip_runtime.h>
#include <hip/hip_bf16.h>
#include <math.h>

typedef __bf16 bf16;
typedef __bf16 bf16x4 __attribute__((ext_vector_type(4)));
typedef __bf16 bf16x8 __attribute__((ext_vector_type(8)));
typedef float f32x4 __attribute__((ext_vector_type(4)));

#define SEQ 1024
#define DMODEL 1024

// async global->LDS DMA, 16B per lane, dest = wave-uniform base + lane*16
__device__ __forceinline__ void gld_lds16(const bf16* g, bf16* l) {
    __builtin_amdgcn_global_load_lds(
        (const __attribute__((address_space(1))) unsigned int*)g,
        (__attribute__((address_space(3))) unsigned int*)l, 16, 0, 0);
}

// ---------------------------------------------------------------------------
// Fused transpose + fp32->bf16 convert: out[n*K + k] = (bf16)in[k*N + n]
// ---------------------------------------------------------------------------
__global__ void transpose_f2b(const float* __restrict__ in, bf16* __restrict__ out,
                              int K, int N) {
    __shared__ float tile[32][33];
    int n0 = blockIdx.x * 32, k0 = blockIdx.y * 32;
    int tx = threadIdx.x, ty = threadIdx.y;
#pragma unroll
    for (int i = 0; i < 4; ++i) {
        int kk = ty + i * 8;
        tile[kk][tx] = in[(size_t)(k0 + kk) * N + n0 + tx];
    }
    __syncthreads();
#pragma unroll
    for (int i = 0; i < 4; ++i) {
        int nn = ty + i * 8;
        out[(size_t)(n0 + nn) * K + k0 + tx] = (bf16)tile[tx][nn];
    }
}

// ---------------------------------------------------------------------------
// LayerNorm: fp32 in -> bf16 out. One row (D=1024) per 256-thread block.
// ---------------------------------------------------------------------------
__global__ void ln_f2b(const float* __restrict__ x, const float* __restrict__ g,
                       const float* __restrict__ bta, bf16* __restrict__ y) {
    int row = blockIdx.x, t = threadIdx.x;
    const float* xr = x + (size_t)row * DMODEL;
    float v[4];
#pragma unroll
    for (int i = 0; i < 4; ++i) v[i] = xr[t * 4 + i];
    float s = v[0] + v[1] + v[2] + v[3];
    float s2 = v[0] * v[0] + v[1] * v[1] + v[2] * v[2] + v[3] * v[3];
#pragma unroll
    for (int off = 32; off > 0; off >>= 1) {
        s += __shfl_down(s, off, 64);
        s2 += __shfl_down(s2, off, 64);
    }
    __shared__ float ws1[4], ws2[4];
    __shared__ float mu_s, rstd_s;
    int lane = t & 63, wv = t >> 6;
    if (lane == 0) { ws1[wv] = s; ws2[wv] = s2; }
    __syncthreads();
    if (t == 0) {
        float S1 = ws1[0] + ws1[1] + ws1[2] + ws1[3];
        float S2 = ws2[0] + ws2[1] + ws2[2] + ws2[3];
        float mu = S1 * (1.0f / DMODEL);
        float var = S2 * (1.0f / DMODEL) - mu * mu;
        mu_s = mu;
        rstd_s = rsqrtf(var + 1e-5f);
    }
    __syncthreads();
    float mu = mu_s, rstd = rstd_s;
    bf16* yr = y + (size_t)row * DMODEL;
#pragma unroll
    for (int i = 0; i < 4; ++i) {
        int d = t * 4 + i;
        float o = (v[i] - mu) * rstd * g[d] + bta[d];
        yr[d] = (bf16)o;
    }
}

// ---------------------------------------------------------------------------
// GEMM (128x128, m97 structure): C[M,N] = A[M,K](bf16) @ Bt[N,K](bf16)^T + bias
// mode: 0 = bf16 out, 1 = bf16 out + exact GELU, 2 = fp32 out
// R5 verdict: the 4-phase 256^2 variant was ~48us SLOWER than this routing
// (barrier density 2.25x m201, prefetch depth 2 vs 6, 1 block/CU) -> all
// GEMMs routed here again.
// ---------------------------------------------------------------------------
#define BM 128
#define BN 128
#define BK 32

__global__ __launch_bounds__(256, 2) void gemm_bt(
    const bf16* __restrict__ A, const bf16* __restrict__ Bt,
    const float* __restrict__ bias, void* __restrict__ Cv,
    int M, int N, int K, int mode) {
    __shared__ bf16 sA[BM * BK];   // row-major, 64B rows, chunk-swizzled
    __shared__ bf16 sB[BN * BK];
    int t = threadIdx.x;
    int lane = t & 63, wave = t >> 6;
    int wr = wave >> 1, wc = wave & 1;
    int m0 = blockIdx.y * BM, n0 = blockIdx.x * BN;
    const bf16* Ap = A + (size_t)m0 * K;
    const bf16* Bp = Bt + (size_t)n0 * K;

    int srow = wave * 16 + (lane >> 2);
    int schunk = lane & 3;
    int gcoff = (schunk ^ (srow & 3)) * 8;
    const bf16* gA0 = Ap + (size_t)srow * K + gcoff;
    const bf16* gA1 = Ap + (size_t)(srow + 64) * K + gcoff;
    const bf16* gB0 = Bp + (size_t)srow * K + gcoff;
    const bf16* gB1 = Bp + (size_t)(srow + 64) * K + gcoff;
    bf16* lA0 = sA + wave * 512;
    bf16* lA1 = sA + 2048 + wave * 512;
    bf16* lB0 = sB + wave * 512;
    bf16* lB1 = sB + 2048 + wave * 512;

    f32x4 acc[4][4];
#pragma unroll
    for (int i = 0; i < 4; ++i)
#pragma unroll
        for (int j = 0; j < 4; ++j) acc[i][j] = (f32x4){0.f, 0.f, 0.f, 0.f};

    int mq = lane & 15, quad = lane >> 4;
    int csw = (quad ^ (mq & 3)) * 8;

    for (int k0 = 0; k0 < K; k0 += BK) {
        __syncthreads();
        gld_lds16(gA0 + k0, lA0);
        gld_lds16(gA1 + k0, lA1);
        gld_lds16(gB0 + k0, lB0);
        gld_lds16(gB1 + k0, lB1);
        __syncthreads();
        bf16x8 af[4], bfr[4];
#pragma unroll
        for (int i = 0; i < 4; ++i)
            af[i] = *(const bf16x8*)&sA[(wr * 64 + i * 16 + mq) * BK + csw];
#pragma unroll
        for (int j = 0; j < 4; ++j)
            bfr[j] = *(const bf16x8*)&sB[(wc * 64 + j * 16 + mq) * BK + csw];
#pragma unroll
        for (int i = 0; i < 4; ++i)
#pragma unroll
            for (int j = 0; j < 4; ++j)
                acc[i][j] = __builtin_amdgcn_mfma_f32_16x16x32_bf16(af[i], bfr[j], acc[i][j], 0, 0, 0);
    }

    int cq = lane & 15, rq = (lane >> 4) * 4;
#pragma unroll
    for (int i = 0; i < 4; ++i) {
        int row = m0 + wr * 64 + i * 16 + rq;
#pragma unroll
        for (int j = 0; j < 4; ++j) {
            int col = n0 + wc * 64 + j * 16 + cq;
            float bv = bias ? bias[col] : 0.0f;
#pragma unroll
            for (int r = 0; r < 4; ++r) {
                float v = acc[i][j][r] + bv;
                if (mode == 1) v = 0.5f * v * (1.0f + erff(v * 0.70710678118654752f));
                size_t idx = (size_t)(row + r) * N + col;
                if (mode == 2) ((float*)Cv)[idx] = v;
                else           ((bf16*)Cv)[idx] = (bf16)v;
            }
        }
    }
}

// ---------------------------------------------------------------------------
// MFMA flash attention v3. Block = one (b,h) x 64 Q rows; 4 waves x 16 rows.
// R5 counters: 141us, MfmaUtil 10%, VALUBusy 61%, FETCH 24.7MB -> DS-issue
// bound, not fetch bound. v3 changes (QK^T/softmax/P only; PV + output
// identical to verified v2):
//  - SWAPPED QK^T: s[g] = mfma(K_frag, Q_frag). C col=lane&15 becomes the
//    q-row, so lane (m,quad) holds P[key=g*16+quad*4+r][q=m] — its OWN
//    q-row's scores. Same K/Q LDS reads (operand order swap only).
//  - lane-local softmax: 31 fmax + 2 shfl_xor(16,32) for row-max (was 32
//    shfl chains); one m_run/l_run scalar per lane; alpha redistributed to
//    o_acc rows by 4 shfl.
//  - P-write: 8x ds_write_b64 at Plds[m][g*16+quad*4] (keys contiguous per
//    lane) instead of 32 scalar b16. PV read Plds[m][kc*32+quad*8] unchanged.
// Next (after this is adjudicated): V-scatter (32 b16/thread/tile, ~40% of
// DS issue) -> ds_read_b64_tr_b16 with m156 subtiled layout.
// ---------------------------------------------------------------------------
#define KVB 128
#define LDK2 72     // Klds row pad (d=64 -> 72)
#define LDP 136     // Vt/P row pad (key=128 -> 136)

__global__ __launch_bounds__(256, 2) void attn_mfma(const bf16* __restrict__ qkv,
                                                    bf16* __restrict__ ao) {
    __shared__ bf16 Klds[KVB][LDK2];    // [key][d]   18,432 B
    __shared__ bf16 Vtlds[64][LDP];     // [d][key]   17,408 B
    __shared__ bf16 Plds[4][16][LDP];   // per-wave P [q-row][key] 17,408 B
    int t = threadIdx.x, lane = t & 63, wave = t >> 6;

    // XCD swizzle: 256 consecutive flat ids per XCD -> all 16 q-tiles of a
    // (b,h) share one L2 copy of K/V (R5: FETCH 139->24.7 MB).
    int f = (int)blockIdx.y * (int)gridDim.x + (int)blockIdx.x;  // 0..2047
    int wg = (f & 7) * 256 + (f >> 3);
    int bh = wg >> 4, bb = bh >> 4, h = bh & 15;
    int q0 = (wg & 15) * 64;

    const bf16* base = qkv + (size_t)bb * SEQ * 3072;
    int m = lane & 15, quad = lane >> 4;
    int kq = quad * 8;

    bf16x8 qf[2];
    {
        int qrow = q0 + wave * 16 + m;
        const bf16* p = base + (size_t)qrow * 3072 + h * 64;
#pragma unroll
        for (int c = 0; c < 2; ++c) {
            bf16x8 tmp = *(const bf16x8*)(p + c * 32 + kq);
#pragma unroll
            for (int j = 0; j < 8; ++j) qf[c][j] = (bf16)((float)tmp[j] * 0.125f);
        }
    }

    float m_run = -3e38f, l_run = 0.f;
    f32x4 o_acc[4];
#pragma unroll
    for (int g = 0; g < 4; ++g) o_acc[g] = (f32x4){0.f, 0.f, 0.f, 0.f};

    // staging: thread covers K/V rows skey+{0,32,64,96}, d-slice sd0..sd0+8
    int skey = t >> 3, sd0 = (t & 7) * 8;
    int rot = t & 7;
    const bf16* pk0 = base + (size_t)skey * 3072 + 1024 + h * 64 + sd0;
    const bf16* pv0 = base + (size_t)skey * 3072 + 2048 + h * 64 + sd0;

    bf16x8 kreg[4], vreg[4];

#define LOADKV(kt2) do { \
    const bf16* pk = pk0 + (size_t)(kt2) * KVB * 3072; \
    const bf16* pv = pv0 + (size_t)(kt2) * KVB * 3072; \
    _Pragma("unroll") for (int c = 0; c < 4; ++c) { \
        kreg[c] = *(const bf16x8*)(pk + (size_t)c * 32 * 3072); \
        vreg[c] = *(const bf16x8*)(pv + (size_t)c * 32 * 3072); } \
} while (0)
#define WRITEKV() do { \
    _Pragma("unroll") for (int c = 0; c < 4; ++c) { \
        *(bf16x8*)&Klds[skey + c * 32][sd0] = kreg[c]; \
        _Pragma("unroll") for (int ii = 0; ii < 8; ++ii) { \
            int j = (ii + rot) & 7; \
            Vtlds[sd0 + j][skey + c * 32] = vreg[c][j]; } } \
} while (0)

    // prologue: tile 0 -> LDS
    LOADKV(0);
    WRITEKV();
    __syncthreads();

    for (int kt = 0; kt < SEQ / KVB; ++kt) {   // 8 iterations
        if (kt + 1 < SEQ / KVB) LOADKV(kt + 1);   // T14: issue early

        // swapped QK^T: s[g][r] = P[key=g*16+quad*4+r][q=m]
        f32x4 s[8];
#pragma unroll
        for (int g = 0; g < 8; ++g) {
            bf16x8 b0 = *(const bf16x8*)&Klds[g * 16 + m][kq];
            bf16x8 b1 = *(const bf16x8*)&Klds[g * 16 + m][32 + kq];
            s[g] = (f32x4){0.f, 0.f, 0.f, 0.f};
            s[g] = __builtin_amdgcn_mfma_f32_16x16x32_bf16(b0, qf[0], s[g], 0, 0, 0);
            s[g] = __builtin_amdgcn_mfma_f32_16x16x32_bf16(b1, qf[1], s[g], 0, 0, 0);
        }

        // lane-local online softmax for q-row m (32 in-lane keys + quad
        // partition of the 128-key row via xor-16/32)
        {
            float mx = s[0][0];
#pragma unroll
            for (int g = 0; g < 8; ++g)
#pragma unroll
                for (int r = 0; r < 4; ++r) mx = fmaxf(mx, s[g][r]);
            mx = fmaxf(mx, __shfl_xor(mx, 16, 64));
            mx = fmaxf(mx, __shfl_xor(mx, 32, 64));
            float m_new = fmaxf(m_run, mx);
            float alpha = __expf(m_run - m_new);
            m_run = m_new;
            float rs = 0.f;
#pragma unroll
            for (int g = 0; g < 8; ++g)
#pragma unroll
                for (int r = 0; r < 4; ++r) {
                    float p = __expf(s[g][r] - m_new);
                    s[g][r] = p;
                    rs += p;
                }
            rs += __shfl_xor(rs, 16, 64);
            rs += __shfl_xor(rs, 32, 64);
            l_run = l_run * alpha + rs;
            // redistribute alpha (row m -> rows quad*4+r held by this lane's acc)
            float av[4];
#pragma unroll
            for (int r = 0; r < 4; ++r) av[r] = __shfl(alpha, quad * 4 + r, 64);
#pragma unroll
            for (int g = 0; g < 4; ++g)
#pragma unroll
                for (int r = 0; r < 4; ++r) o_acc[g][r] *= av[r];
        }

        // P -> LDS: keys g*16+quad*4+{0..3} of row m, one b64 per g
#pragma unroll
        for (int g = 0; g < 8; ++g) {
            bf16x4 pw = {(bf16)s[g][0], (bf16)s[g][1], (bf16)s[g][2], (bf16)s[g][3]};
            *(bf16x4*)&Plds[wave][m][g * 16 + quad * 4] = pw;
        }

        // PV: 4 key-chunks of 32 (identical to verified v2)
#pragma unroll
        for (int kc = 0; kc < 4; ++kc) {
            bf16x8 pf = *(const bf16x8*)&Plds[wave][m][kc * 32 + kq];
#pragma unroll
            for (int dg = 0; dg < 4; ++dg) {
                bf16x8 vf = *(const bf16x8*)&Vtlds[dg * 16 + m][kc * 32 + kq];
                o_acc[dg] = __builtin_amdgcn_mfma_f32_16x16x32_bf16(pf, vf, o_acc[dg], 0, 0, 0);
            }
        }

        __syncthreads();                         // all waves done with tile kt
        if (kt + 1 < SEQ / KVB) {
            WRITEKV();                           // regs -> LDS
        }
        __syncthreads();                         // tile kt+1 visible
    }

#undef LOADKV
#undef WRITEKV

#pragma unroll
    for (int r = 0; r < 4; ++r) {
        int row = q0 + wave * 16 + quad * 4 + r;
        float rl = 1.0f / __shfl(l_run, quad * 4 + r, 64);
        bf16* op = ao + ((size_t)bb * SEQ + row) * DMODEL + h * 64;
#pragma unroll
        for (int g = 0; g < 4; ++g) op[g * 16 + m] = (bf16)(o_acc[g][r] * rl);
    }
}

// ---------------------------------------------------------------------------
// kernel_launch — fp32 I/O, bf16 internal. ws peak 56 MiB; d_out (32 MB) used
// as scratch (xn/ao in [0,16M), x2n in [16M,32M), final fp32 out last).
// All GEMMs on gemm_bt (128^2) — R5 showed the 4-phase 256^2 was a net loss.
// ---------------------------------------------------------------------------
extern "C" void kernel_launch(void* const* d_in, const int* in_sizes, int n_in,
                              void* d_out, int out_size, void* d_ws, size_t ws_size,
                              hipStream_t stream) {
    const float* x     = (const float*)d_in[0];
    const float* ln1_g = (const float*)d_in[1];
    const float* ln1_b = (const float*)d_in[2];
    const float* w_qkv = (const float*)d_in[3];
    const float* w_out = (const float*)d_in[4];
    const float* b_out = (const float*)d_in[5];
    const float* ln2_g = (const float*)d_in[6];
    const float* ln2_b = (const float*)d_in[7];
    const float* w1    = (const float*)d_in[8];
    const float* b1    = (const float*)d_in[9];
    const float* w2    = (const float*)d_in[10];
    const float* b2    = (const float*)d_in[11];
    float* out = (float*)d_out;
    char* ws = (char*)d_ws;
    char* outc = (char*)d_out;

    bf16* wqkvT = (bf16*)(ws + (0ull << 20));
    bf16* woutT = (bf16*)(ws + (6ull << 20));
    bf16* qkv   = (bf16*)(ws + (8ull << 20));
    bf16* w1T   = (bf16*)(ws + (8ull << 20));    // over dead qkv (after attn)
    bf16* w2T   = (bf16*)(ws + (16ull << 20));   // over dead qkv (after attn)
    float* x2   = (float*)(ws + (24ull << 20));  // over dead qkv (after attn)
    bf16* hbuf  = (bf16*)(ws + (24ull << 20));   // over dead x2 (after ln2)
    bf16* xn    = (bf16*)(outc + 0);             // d_out as scratch
    bf16* ao    = (bf16*)(outc + 0);             // xn dead
    bf16* x2n   = (bf16*)(outc + (16ull << 20)); // upper half of d_out

    dim3 tb(32, 8);
    transpose_f2b<<<dim3(3072 / 32, 1024 / 32), tb, 0, stream>>>(w_qkv, wqkvT, 1024, 3072);
    transpose_f2b<<<dim3(1024 / 32, 1024 / 32), tb, 0, stream>>>(w_out, woutT, 1024, 1024);

    ln_f2b<<<8192, 256, 0, stream>>>(x, ln1_g, ln1_b, xn);
    gemm_bt<<<dim3(3072 / 128, 8192 / 128), 256, 0, stream>>>(xn, wqkvT, nullptr, qkv,
                                                              8192, 3072, 1024, 0);
    attn_mfma<<<dim3(SEQ / 64, 128), 256, 0, stream>>>(qkv, ao);

    transpose_f2b<<<dim3(4096 / 32, 1024 / 32), tb, 0, stream>>>(w1, w1T, 1024, 4096);
    transpose_f2b<<<dim3(1024 / 32, 4096 / 32), tb, 0, stream>>>(w2, w2T, 4096, 1024);

    gemm_bt<<<dim3(1024 / 128, 8192 / 128), 256, 0, stream>>>(ao, woutT, b_out, x2,
                                                              8192, 1024, 1024, 2);
    ln_f2b<<<8192, 256, 0, stream>>>(x2, ln2_g, ln2_b, x2n);

    for (int c = 0; c < 2; ++c) {
        const bf16* a1 = x2n + (size_t)c * 4096 * 1024;
        float* oc = out + (size_t)c * 4096 * 1024;
        gemm_bt<<<dim3(4096 / 128, 4096 / 128), 256, 0, stream>>>(a1, w1T, b1, hbuf,
                                                                  4096, 4096, 1024, 1);
        gemm_bt<<<dim3(1024 / 128, 4096 / 128), 256, 0, stream>>>(hbuf, w2T, b2, oc,
                                                                  4096, 1024, 4096, 2);
    }
}